// Round 1
// baseline (12716.077 us; speedup 1.0000x reference)
//
#include <hip/hip_runtime.h>
#include <cstdint>
#include <cstddef>

#define SEQ 1024
#define DMODEL 768
#define NHEAD 12
#define DHEAD 64
#define NLAYER 4
#define NEXP 8
#define DHID 1536
#define VOCAB 512
#define NTOK 4096   // B*S

// ---------------- embed ----------------
__global__ __launch_bounds__(256) void embed_kernel(const int* __restrict__ x,
    const float* __restrict__ tok, const float* __restrict__ pos, float* __restrict__ h) {
  int i = blockIdx.x * 256 + threadIdx.x;  // over NTOK*DMODEL
  int n = i / DMODEL, d = i - n * DMODEL;
  int s = n & (SEQ - 1);
  h[i] = tok[(size_t)x[n] * DMODEL + d] + pos[(size_t)s * DMODEL + d];
}

// ---------------- layernorm (one block per row) ----------------
__global__ __launch_bounds__(256) void ln_kernel(const float* __restrict__ x,
    const float* __restrict__ g, const float* __restrict__ b, float* __restrict__ y) {
  int row = blockIdx.x;
  const float* xr = x + (size_t)row * DMODEL;
  int t = threadIdx.x;
  float v0 = xr[t], v1 = xr[t + 256], v2 = xr[t + 512];
  float s = v0 + v1 + v2;
  float s2 = v0 * v0 + v1 * v1 + v2 * v2;
  for (int off = 32; off; off >>= 1) { s += __shfl_down(s, off); s2 += __shfl_down(s2, off); }
  __shared__ float rs[4], rq[4];
  if ((t & 63) == 0) { rs[t >> 6] = s; rq[t >> 6] = s2; }
  __syncthreads();
  float S  = rs[0] + rs[1] + rs[2] + rs[3];
  float S2 = rq[0] + rq[1] + rq[2] + rq[3];
  float m = S * (1.f / DMODEL);
  float var = S2 * (1.f / DMODEL) - m * m;
  float r = rsqrtf(var + 1e-5f);
  float* yr = y + (size_t)row * DMODEL;
  yr[t]       = (v0 - m) * r * g[t]       + b[t];
  yr[t + 256] = (v1 - m) * r * g[t + 256] + b[t + 256];
  yr[t + 512] = (v2 - m) * r * g[t + 512] + b[t + 512];
}

// ---------------- tiled fp32 GEMM: C[M,N] = A[M,K] @ B(+bias) ----------------
#define BM 64
#define BN 64
#define BK 16
template<bool TRANSB, bool RESID>
__global__ __launch_bounds__(256) void gemm_std(
    const float* __restrict__ A, const float* __restrict__ Bm,
    const float* __restrict__ bias, float* __restrict__ C,
    int M, int Nn, int K)
{
  __shared__ float As[BK][BM + 1];
  __shared__ float Bs[BK][BN + 1];
  int bm = blockIdx.y * BM, bn = blockIdx.x * BN;
  int tid = threadIdx.x;
  int tr = tid >> 4, tc = tid & 15;
  float acc[4][4] = {};
  for (int k0 = 0; k0 < K; k0 += BK) {
    for (int i = tid; i < BM * BK; i += 256) {
      int r = i >> 4, c = i & 15;
      As[c][r] = A[(size_t)(bm + r) * K + k0 + c];
    }
    for (int i = tid; i < BK * BN; i += 256) {
      int r = i >> 6, c = i & 63;
      Bs[r][c] = TRANSB ? Bm[(size_t)(bn + c) * K + k0 + r]
                        : Bm[(size_t)(k0 + r) * Nn + bn + c];
    }
    __syncthreads();
#pragma unroll
    for (int kk = 0; kk < BK; kk++) {
      float a[4], bb[4];
#pragma unroll
      for (int i = 0; i < 4; i++) a[i] = As[kk][tr * 4 + i];
#pragma unroll
      for (int j = 0; j < 4; j++) bb[j] = Bs[kk][tc * 4 + j];
#pragma unroll
      for (int i = 0; i < 4; i++)
#pragma unroll
        for (int j = 0; j < 4; j++) acc[i][j] += a[i] * bb[j];
    }
    __syncthreads();
  }
#pragma unroll
  for (int i = 0; i < 4; i++) {
    int r = bm + tr * 4 + i;
    float* Crow = C + (size_t)r * Nn;
#pragma unroll
    for (int j = 0; j < 4; j++) {
      int c = bn + tc * 4 + j;
      float v = acc[i][j] + (bias ? bias[c] : 0.f);
      if (RESID) v += Crow[c];
      Crow[c] = v;
    }
  }
}

// ---------------- MoE gathered GEMM ----------------
__device__ __forceinline__ float gelu_f(float x) {
  float x3 = x * x * x;
  return 0.5f * x * (1.f + tanhf(0.7978845608028654f * (x + 0.044715f * x3)));
}

template<bool GELU, bool SCALE>
__global__ __launch_bounds__(256) void gemm_moe(
    const float* __restrict__ A, const float* __restrict__ Bbase,
    const float* __restrict__ biasBase, float* __restrict__ C,
    const int* __restrict__ entries, const int* __restrict__ counts,
    const float* __restrict__ tokw, int Nn, int K)
{
  int e = blockIdx.z;
  int cnt = counts[e];
  int bm = blockIdx.y * BM;
  if (bm >= cnt) return;
  const float* Bm = Bbase + (size_t)e * K * Nn;
  const float* bias = biasBase + (size_t)e * Nn;
  const int* list = entries + e * NTOK;
  int bn = blockIdx.x * BN;
  int tid = threadIdx.x;
  int tr = tid >> 4, tc = tid & 15;
  __shared__ float As[BK][BM + 1];
  __shared__ float Bs[BK][BN + 1];
  __shared__ int rowent[BM];
  for (int i = tid; i < BM; i += 256) {
    int gr = bm + i;
    rowent[i] = (gr < cnt) ? list[gr] : -1;
  }
  __syncthreads();
  float acc[4][4] = {};
  for (int k0 = 0; k0 < K; k0 += BK) {
    for (int i = tid; i < BM * BK; i += 256) {
      int r = i >> 4, c = i & 15;
      int ent = rowent[r];
      float v = 0.f;
      if (ent >= 0) {
        int arow = GELU ? (ent >> 1) : ent;  // w1 gathers token rows, w2 gathers H1 rows
        v = A[(size_t)arow * K + k0 + c];
      }
      As[c][r] = v;
    }
    for (int i = tid; i < BK * BN; i += 256) {
      int r = i >> 6, c = i & 63;
      Bs[r][c] = Bm[(size_t)(k0 + r) * Nn + bn + c];
    }
    __syncthreads();
#pragma unroll
    for (int kk = 0; kk < BK; kk++) {
      float a[4], bb[4];
#pragma unroll
      for (int i = 0; i < 4; i++) a[i] = As[kk][tr * 4 + i];
#pragma unroll
      for (int j = 0; j < 4; j++) bb[j] = Bs[kk][tc * 4 + j];
#pragma unroll
      for (int i = 0; i < 4; i++)
#pragma unroll
        for (int j = 0; j < 4; j++) acc[i][j] += a[i] * bb[j];
    }
    __syncthreads();
  }
#pragma unroll
  for (int i = 0; i < 4; i++) {
    int ent = rowent[tr * 4 + i];
    if (ent < 0) continue;
    float scl = SCALE ? tokw[ent] : 1.f;
    float* Crow = C + (size_t)ent * Nn;
#pragma unroll
    for (int j = 0; j < 4; j++) {
      int c = bn + tc * 4 + j;
      float v = acc[i][j] + bias[c];
      if (GELU) v = gelu_f(v);
      if (SCALE) v *= scl;
      Crow[c] = v;
    }
  }
}

// ---------------- attention: one block per (b,h,q) row ----------------
__global__ __launch_bounds__(256) void attn_kernel(const float* __restrict__ qkv,
                                                   float* __restrict__ out) {
  int q  = blockIdx.x & (SEQ - 1);
  int bh = blockIdx.x >> 10;
  int hh = bh % NHEAD, b = bh / NHEAD;
  int n0 = b * SEQ;
  int t = threadIdx.x;
  __shared__ float qs[DHEAD];
  __shared__ float sc[SEQ];
  __shared__ float red[4];
  __shared__ float red2[4];
  __shared__ float pr[256];
  const float* base = qkv + (size_t)n0 * (3 * DMODEL);
  if (t < DHEAD) qs[t] = base[(size_t)q * (3 * DMODEL) + hh * DHEAD + t];
  __syncthreads();
  float lm = -3.4e38f;
  for (int k = t; k <= q; k += 256) {
    const float* kr = base + (size_t)k * (3 * DMODEL) + DMODEL + hh * DHEAD;
    float s = 0.f;
#pragma unroll
    for (int d = 0; d < DHEAD; d++) s += qs[d] * kr[d];
    s *= 0.125f;  // 1/sqrt(64)
    sc[k] = s;
    lm = fmaxf(lm, s);
  }
  for (int off = 32; off; off >>= 1) lm = fmaxf(lm, __shfl_down(lm, off));
  if ((t & 63) == 0) red[t >> 6] = lm;
  __syncthreads();
  float M = fmaxf(fmaxf(red[0], red[1]), fmaxf(red[2], red[3]));
  float ls = 0.f;
  for (int k = t; k <= q; k += 256) {
    float p = expf(sc[k] - M);
    sc[k] = p;
    ls += p;
  }
  for (int off = 32; off; off >>= 1) ls += __shfl_down(ls, off);
  if ((t & 63) == 0) red2[t >> 6] = ls;
  __syncthreads();  // also makes sc[] updates visible to all
  float rinv = 1.f / (red2[0] + red2[1] + red2[2] + red2[3]);
  int d = t & 63, kg = t >> 6;
  float acc = 0.f;
  for (int k = kg; k <= q; k += 4)
    acc += sc[k] * base[(size_t)k * (3 * DMODEL) + 2 * DMODEL + hh * DHEAD + d];
  pr[t] = acc;
  __syncthreads();
  if (t < 64) {
    float v = (pr[t] + pr[t + 64] + pr[t + 128] + pr[t + 192]) * rinv;
    out[(size_t)(n0 + q) * DMODEL + hh * DHEAD + t] = v;
  }
}

// ---------------- gate: 1 thread per token ----------------
__global__ __launch_bounds__(256) void gate_kernel(const float* __restrict__ xln,
    const float* __restrict__ gw, const float* __restrict__ gb,
    int* __restrict__ counts, int* __restrict__ entries, float* __restrict__ tokw) {
  int n = blockIdx.x * 256 + threadIdx.x;
  if (n >= NTOK) return;
  const float* xr = xln + (size_t)n * DMODEL;
  float gl[NEXP];
#pragma unroll
  for (int e = 0; e < NEXP; e++) gl[e] = gb[e];
  for (int dd = 0; dd < DMODEL; dd++) {
    float xv = xr[dd];
#pragma unroll
    for (int e = 0; e < NEXP; e++) gl[e] += xv * gw[dd * NEXP + e];
  }
  float mx = gl[0];
#pragma unroll
  for (int e = 1; e < NEXP; e++) mx = fmaxf(mx, gl[e]);
  float ex[NEXP];
#pragma unroll
  for (int e = 0; e < NEXP; e++) ex[e] = expf(gl[e] - mx);
  int i0 = 0; float v0 = ex[0];
#pragma unroll
  for (int e = 1; e < NEXP; e++) if (ex[e] > v0) { v0 = ex[e]; i0 = e; }
  int i1 = -1; float v1 = -1.f;
#pragma unroll
  for (int e = 0; e < NEXP; e++) if (e != i0 && ex[e] > v1) { v1 = ex[e]; i1 = e; }
  float wsum = v0 + v1;            // softmax denominator cancels in renorm
  float w0 = v0 / wsum, w1 = v1 / wsum;
  int p0 = atomicAdd(&counts[i0], 1);
  entries[i0 * NTOK + p0] = n * 2 + 0;
  tokw[n * 2 + 0] = w0;
  int p1 = atomicAdd(&counts[i1], 1);
  entries[i1 * NTOK + p1] = n * 2 + 1;
  tokw[n * 2 + 1] = w1;
}

__global__ void zero_counts(int* c) { if (threadIdx.x < NEXP) c[threadIdx.x] = 0; }

// ---------------- combine: h += eo[slot0] + eo[slot1] ----------------
__global__ __launch_bounds__(256) void combine_kernel(float* __restrict__ h,
                                                      const float* __restrict__ eo) {
  int i = blockIdx.x * 256 + threadIdx.x;
  int n = i / DMODEL, d = i - n * DMODEL;
  h[i] += eo[(size_t)(n * 2) * DMODEL + d] + eo[(size_t)(n * 2 + 1) * DMODEL + d];
}

extern "C" void kernel_launch(void* const* d_in, const int* in_sizes, int n_in,
                              void* d_out, int out_size, void* d_ws, size_t ws_size,
                              hipStream_t stream) {
  const int*   x       = (const int*)d_in[0];
  const float* tok_emb = (const float*)d_in[1];
  const float* pos_emb = (const float*)d_in[2];
  const float* ln1_g   = (const float*)d_in[3];
  const float* ln1_b   = (const float*)d_in[4];
  const float* qkv_w   = (const float*)d_in[5];
  const float* qkv_b   = (const float*)d_in[6];
  const float* proj_w  = (const float*)d_in[7];
  const float* proj_b  = (const float*)d_in[8];
  const float* ln2_g   = (const float*)d_in[9];
  const float* ln2_b   = (const float*)d_in[10];
  const float* gate_w  = (const float*)d_in[11];
  const float* gate_b  = (const float*)d_in[12];
  const float* w1      = (const float*)d_in[13];
  const float* b1      = (const float*)d_in[14];
  const float* w2      = (const float*)d_in[15];
  const float* b2      = (const float*)d_in[16];
  const float* lnf_g   = (const float*)d_in[17];
  const float* lnf_b   = (const float*)d_in[18];
  float* out = (float*)d_out;

  const size_t ND = (size_t)NTOK * DMODEL;            // 3,145,728 floats
  float* h    = (float*)d_ws;
  float* xln  = h + ND;
  float* R    = xln + ND;                              // qkv (3*ND) / H1 (2N*DHID)
  float* R2   = R + (size_t)2 * NTOK * DHID;           // attn_out (ND) / eo (2N*D)
  float* tokw = R2 + (size_t)2 * NTOK * DMODEL;
  int* counts  = (int*)(tokw + 2 * NTOK);
  int* entries = counts + NEXP;

  float* qkvbuf   = R;
  float* H1       = R;
  float* attn_out = R2;
  float* eo       = R2;

  dim3 blk(256);
  embed_kernel<<<ND / 256, blk, 0, stream>>>(x, tok_emb, pos_emb, h);
  for (int l = 0; l < NLAYER; l++) {
    ln_kernel<<<NTOK, blk, 0, stream>>>(h, ln1_g + l * DMODEL, ln1_b + l * DMODEL, xln);
    gemm_std<false, false><<<dim3(36, 64), blk, 0, stream>>>(
        xln, qkv_w + (size_t)l * DMODEL * 3 * DMODEL, qkv_b + l * 3 * DMODEL,
        qkvbuf, NTOK, 3 * DMODEL, DMODEL);
    attn_kernel<<<4 * NHEAD * SEQ, blk, 0, stream>>>(qkvbuf, attn_out);
    gemm_std<false, true><<<dim3(12, 64), blk, 0, stream>>>(
        attn_out, proj_w + (size_t)l * DMODEL * DMODEL, proj_b + l * DMODEL,
        h, NTOK, DMODEL, DMODEL);
    ln_kernel<<<NTOK, blk, 0, stream>>>(h, ln2_g + l * DMODEL, ln2_b + l * DMODEL, xln);
    zero_counts<<<1, 64, 0, stream>>>(counts);
    gate_kernel<<<NTOK / 256, blk, 0, stream>>>(
        xln, gate_w + (size_t)l * DMODEL * NEXP, gate_b + l * NEXP, counts, entries, tokw);
    gemm_moe<true, false><<<dim3(DHID / 64, 64, NEXP), blk, 0, stream>>>(
        xln, w1 + (size_t)l * NEXP * DMODEL * DHID, b1 + (size_t)l * NEXP * DHID,
        H1, entries, counts, tokw, DHID, DMODEL);
    gemm_moe<false, true><<<dim3(DMODEL / 64, 64, NEXP), blk, 0, stream>>>(
        H1, w2 + (size_t)l * NEXP * DHID * DMODEL, b2 + (size_t)l * NEXP * DMODEL,
        eo, entries, counts, tokw, DMODEL, DHID);
    combine_kernel<<<ND / 256, blk, 0, stream>>>(h, eo);
  }
  ln_kernel<<<NTOK, blk, 0, stream>>>(h, lnf_g, lnf_b, xln);
  gemm_std<true, false><<<dim3(VOCAB / 64, 64), blk, 0, stream>>>(
      xln, tok_emb, nullptr, out, NTOK, VOCAB, DMODEL);
}

// Round 2
// 8814.657 us; speedup vs baseline: 1.4426x; 1.4426x over previous
//
#include <hip/hip_runtime.h>
#include <cstdint>
#include <cstddef>

#define SEQ 1024
#define DMODEL 768
#define NHEAD 12
#define DHEAD 64
#define NLAYER 4
#define NEXP 8
#define DHID 1536
#define VOCAB 512
#define NTOK 4096   // B*S

// ---------------- embed ----------------
__global__ __launch_bounds__(256) void embed_kernel(const int* __restrict__ x,
    const float* __restrict__ tok, const float* __restrict__ pos, float* __restrict__ h) {
  int i = blockIdx.x * 256 + threadIdx.x;  // over NTOK*DMODEL
  int n = i / DMODEL, d = i - n * DMODEL;
  int s = n & (SEQ - 1);
  h[i] = tok[(size_t)x[n] * DMODEL + d] + pos[(size_t)s * DMODEL + d];
}

// ---------------- layernorm (one block per row) ----------------
__global__ __launch_bounds__(256) void ln_kernel(const float* __restrict__ x,
    const float* __restrict__ g, const float* __restrict__ b, float* __restrict__ y) {
  int row = blockIdx.x;
  const float* xr = x + (size_t)row * DMODEL;
  int t = threadIdx.x;
  float v0 = xr[t], v1 = xr[t + 256], v2 = xr[t + 512];
  float s = v0 + v1 + v2;
  float s2 = v0 * v0 + v1 * v1 + v2 * v2;
  for (int off = 32; off; off >>= 1) { s += __shfl_down(s, off); s2 += __shfl_down(s2, off); }
  __shared__ float rs[4], rq[4];
  if ((t & 63) == 0) { rs[t >> 6] = s; rq[t >> 6] = s2; }
  __syncthreads();
  float S  = rs[0] + rs[1] + rs[2] + rs[3];
  float S2 = rq[0] + rq[1] + rq[2] + rq[3];
  float m = S * (1.f / DMODEL);
  float var = S2 * (1.f / DMODEL) - m * m;
  float r = rsqrtf(var + 1e-5f);
  float* yr = y + (size_t)row * DMODEL;
  yr[t]       = (v0 - m) * r * g[t]       + b[t];
  yr[t + 256] = (v1 - m) * r * g[t + 256] + b[t + 256];
  yr[t + 512] = (v2 - m) * r * g[t + 512] + b[t + 512];
}

// ---------------- tiled fp32 GEMM: C[M,N] = A[M,K] @ B(+bias) ----------------
#define BM 64
#define BN 64
#define BK 16
template<bool TRANSB, bool RESID>
__global__ __launch_bounds__(256) void gemm_std(
    const float* __restrict__ A, const float* __restrict__ Bm,
    const float* __restrict__ bias, float* __restrict__ C,
    int M, int Nn, int K)
{
  __shared__ float As[BK][BM + 1];
  __shared__ float Bs[BK][BN + 1];
  int bm = blockIdx.y * BM, bn = blockIdx.x * BN;
  int tid = threadIdx.x;
  int tr = tid >> 4, tc = tid & 15;
  float acc[4][4] = {};
  for (int k0 = 0; k0 < K; k0 += BK) {
    for (int i = tid; i < BM * BK; i += 256) {
      int r = i >> 4, c = i & 15;
      As[c][r] = A[(size_t)(bm + r) * K + k0 + c];
    }
    for (int i = tid; i < BK * BN; i += 256) {
      int r = i >> 6, c = i & 63;
      Bs[r][c] = TRANSB ? Bm[(size_t)(bn + c) * K + k0 + r]
                        : Bm[(size_t)(k0 + r) * Nn + bn + c];
    }
    __syncthreads();
#pragma unroll
    for (int kk = 0; kk < BK; kk++) {
      float a[4], bb[4];
#pragma unroll
      for (int i = 0; i < 4; i++) a[i] = As[kk][tr * 4 + i];
#pragma unroll
      for (int j = 0; j < 4; j++) bb[j] = Bs[kk][tc * 4 + j];
#pragma unroll
      for (int i = 0; i < 4; i++)
#pragma unroll
        for (int j = 0; j < 4; j++) acc[i][j] += a[i] * bb[j];
    }
    __syncthreads();
  }
#pragma unroll
  for (int i = 0; i < 4; i++) {
    int r = bm + tr * 4 + i;
    float* Crow = C + (size_t)r * Nn;
#pragma unroll
    for (int j = 0; j < 4; j++) {
      int c = bn + tc * 4 + j;
      float v = acc[i][j] + (bias ? bias[c] : 0.f);
      if (RESID) v += Crow[c];
      Crow[c] = v;
    }
  }
}

// ---------------- MoE gathered GEMM ----------------
__device__ __forceinline__ float gelu_f(float x) {
  float x3 = x * x * x;
  return 0.5f * x * (1.f + tanhf(0.7978845608028654f * (x + 0.044715f * x3)));
}

template<bool GELU, bool SCALE>
__global__ __launch_bounds__(256) void gemm_moe(
    const float* __restrict__ A, const float* __restrict__ Bbase,
    const float* __restrict__ biasBase, float* __restrict__ C,
    const int* __restrict__ entries, const int* __restrict__ counts,
    const float* __restrict__ tokw, int Nn, int K)
{
  int e = blockIdx.z;
  int cnt = counts[e];
  int bm = blockIdx.y * BM;
  if (bm >= cnt) return;
  const float* Bm = Bbase + (size_t)e * K * Nn;
  const float* bias = biasBase + (size_t)e * Nn;
  const int* list = entries + e * NTOK;
  int bn = blockIdx.x * BN;
  int tid = threadIdx.x;
  int tr = tid >> 4, tc = tid & 15;
  __shared__ float As[BK][BM + 1];
  __shared__ float Bs[BK][BN + 1];
  __shared__ int rowent[BM];
  for (int i = tid; i < BM; i += 256) {
    int gr = bm + i;
    rowent[i] = (gr < cnt) ? list[gr] : -1;
  }
  __syncthreads();
  float acc[4][4] = {};
  for (int k0 = 0; k0 < K; k0 += BK) {
    for (int i = tid; i < BM * BK; i += 256) {
      int r = i >> 4, c = i & 15;
      int ent = rowent[r];
      float v = 0.f;
      if (ent >= 0) {
        int arow = GELU ? (ent >> 1) : ent;  // w1 gathers token rows, w2 gathers H1 rows
        v = A[(size_t)arow * K + k0 + c];
      }
      As[c][r] = v;
    }
    for (int i = tid; i < BK * BN; i += 256) {
      int r = i >> 6, c = i & 63;
      Bs[r][c] = Bm[(size_t)(k0 + r) * Nn + bn + c];
    }
    __syncthreads();
#pragma unroll
    for (int kk = 0; kk < BK; kk++) {
      float a[4], bb[4];
#pragma unroll
      for (int i = 0; i < 4; i++) a[i] = As[kk][tr * 4 + i];
#pragma unroll
      for (int j = 0; j < 4; j++) bb[j] = Bs[kk][tc * 4 + j];
#pragma unroll
      for (int i = 0; i < 4; i++)
#pragma unroll
        for (int j = 0; j < 4; j++) acc[i][j] += a[i] * bb[j];
    }
    __syncthreads();
  }
#pragma unroll
  for (int i = 0; i < 4; i++) {
    int ent = rowent[tr * 4 + i];
    if (ent < 0) continue;
    float scl = SCALE ? tokw[ent] : 1.f;
    float* Crow = C + (size_t)ent * Nn;
#pragma unroll
    for (int j = 0; j < 4; j++) {
      int c = bn + tc * 4 + j;
      float v = acc[i][j] + bias[c];
      if (GELU) v = gelu_f(v);
      if (SCALE) v *= scl;
      Crow[c] = v;
    }
  }
}

// ---------------- flash attention: one block per (b, h, 64-row q-tile) ----------------
// qkv row layout: [q(768) | k(768) | v(768)], head h occupies cols h*64..h*64+63.
__global__ __launch_bounds__(256) void fattn_kernel(const float* __restrict__ qkv,
                                                    float* __restrict__ out) {
  int qt = blockIdx.x;           // q tile 0..15
  int hh = blockIdx.y;           // head
  int b  = blockIdx.z;           // batch
  int n0 = b * SEQ;
  int q0 = qt * 64;
  const float* base = qkv + (size_t)n0 * (3 * DMODEL);
  int tid = threadIdx.x;
  int tr = tid >> 4, tc = tid & 15;

  __shared__ float Qs[64][65];   // transposed: Qs[d][q], pre-scaled
  __shared__ float Ks[64][65];   // transposed: Ks[d][k]
  __shared__ float Ps[64][65];   // P[q][k]
  __shared__ float Vs[64][64];   // V[k][d]

#pragma unroll
  for (int it = 0; it < 16; it++) {
    int i = tid + it * 256;
    int r = i >> 6, c = i & 63;
    Qs[c][r] = base[(size_t)(q0 + r) * (3 * DMODEL) + hh * DHEAD + c] * 0.125f;
  }

  float m_i[4], l_i[4], O[4][4];
#pragma unroll
  for (int i = 0; i < 4; i++) {
    m_i[i] = -3.4e38f; l_i[i] = 0.f;
#pragma unroll
    for (int j = 0; j < 4; j++) O[i][j] = 0.f;
  }

  for (int kt = 0; kt <= qt; kt++) {
    int k0 = kt * 64;
    __syncthreads();   // previous iteration's Ks/Vs/Ps reads done
#pragma unroll
    for (int it = 0; it < 16; it++) {
      int i = tid + it * 256;
      int r = i >> 6, c = i & 63;
      const float* krow = base + (size_t)(k0 + r) * (3 * DMODEL);
      Ks[c][r] = krow[DMODEL + hh * DHEAD + c];
      Vs[r][c] = krow[2 * DMODEL + hh * DHEAD + c];
    }
    __syncthreads();

    // S = (Q*scale) K^T  — 4x4 per thread
    float s[4][4] = {};
#pragma unroll
    for (int d = 0; d < 64; d++) {
      float a[4], bb[4];
#pragma unroll
      for (int i = 0; i < 4; i++) a[i] = Qs[d][tr * 4 + i];
#pragma unroll
      for (int j = 0; j < 4; j++) bb[j] = Ks[d][tc * 4 + j];
#pragma unroll
      for (int i = 0; i < 4; i++)
#pragma unroll
        for (int j = 0; j < 4; j++) s[i][j] += a[i] * bb[j];
    }
    if (kt == qt) {  // causal mask only on the diagonal tile
#pragma unroll
      for (int i = 0; i < 4; i++)
#pragma unroll
        for (int j = 0; j < 4; j++)
          if (k0 + tc * 4 + j > q0 + tr * 4 + i) s[i][j] = -3.4e38f;
    }

    // online softmax: the 16 lanes with equal tr share each q row
#pragma unroll
    for (int i = 0; i < 4; i++) {
      float rm = fmaxf(fmaxf(s[i][0], s[i][1]), fmaxf(s[i][2], s[i][3]));
#pragma unroll
      for (int off = 1; off < 16; off <<= 1) rm = fmaxf(rm, __shfl_xor(rm, off));
      float mnew = fmaxf(m_i[i], rm);
      float alpha = expf(m_i[i] - mnew);
      float p[4], rsum = 0.f;
#pragma unroll
      for (int j = 0; j < 4; j++) { p[j] = expf(s[i][j] - mnew); rsum += p[j]; }
#pragma unroll
      for (int off = 1; off < 16; off <<= 1) rsum += __shfl_xor(rsum, off);
      l_i[i] = l_i[i] * alpha + rsum;
      m_i[i] = mnew;
#pragma unroll
      for (int j = 0; j < 4; j++) {
        O[i][j] *= alpha;
        Ps[tr * 4 + i][tc * 4 + j] = p[j];
      }
    }
    __syncthreads();

    // O += P V — 4x4 per thread (same tr = same q rows, so alpha bookkeeping is consistent)
#pragma unroll
    for (int kk = 0; kk < 64; kk++) {
      float a[4], bb[4];
#pragma unroll
      for (int i = 0; i < 4; i++) a[i] = Ps[tr * 4 + i][kk];
#pragma unroll
      for (int j = 0; j < 4; j++) bb[j] = Vs[kk][tc * 4 + j];
#pragma unroll
      for (int i = 0; i < 4; i++)
#pragma unroll
        for (int j = 0; j < 4; j++) O[i][j] += a[i] * bb[j];
    }
  }

#pragma unroll
  for (int i = 0; i < 4; i++) {
    float rinv = 1.f / l_i[i];
    float* orow = out + (size_t)(n0 + q0 + tr * 4 + i) * DMODEL + hh * DHEAD;
#pragma unroll
    for (int j = 0; j < 4; j++) orow[tc * 4 + j] = O[i][j] * rinv;
  }
}

// ---------------- gate: 1 thread per token ----------------
__global__ __launch_bounds__(256) void gate_kernel(const float* __restrict__ xln,
    const float* __restrict__ gw, const float* __restrict__ gb,
    int* __restrict__ counts, int* __restrict__ entries, float* __restrict__ tokw) {
  int n = blockIdx.x * 256 + threadIdx.x;
  if (n >= NTOK) return;
  const float* xr = xln + (size_t)n * DMODEL;
  float gl[NEXP];
#pragma unroll
  for (int e = 0; e < NEXP; e++) gl[e] = gb[e];
  for (int dd = 0; dd < DMODEL; dd++) {
    float xv = xr[dd];
#pragma unroll
    for (int e = 0; e < NEXP; e++) gl[e] += xv * gw[dd * NEXP + e];
  }
  float mx = gl[0];
#pragma unroll
  for (int e = 1; e < NEXP; e++) mx = fmaxf(mx, gl[e]);
  float ex[NEXP];
#pragma unroll
  for (int e = 0; e < NEXP; e++) ex[e] = expf(gl[e] - mx);
  int i0 = 0; float v0 = ex[0];
#pragma unroll
  for (int e = 1; e < NEXP; e++) if (ex[e] > v0) { v0 = ex[e]; i0 = e; }
  int i1 = -1; float v1 = -1.f;
#pragma unroll
  for (int e = 0; e < NEXP; e++) if (e != i0 && ex[e] > v1) { v1 = ex[e]; i1 = e; }
  float wsum = v0 + v1;            // softmax denominator cancels in renorm
  float w0 = v0 / wsum, w1 = v1 / wsum;
  int p0 = atomicAdd(&counts[i0], 1);
  entries[i0 * NTOK + p0] = n * 2 + 0;
  tokw[n * 2 + 0] = w0;
  int p1 = atomicAdd(&counts[i1], 1);
  entries[i1 * NTOK + p1] = n * 2 + 1;
  tokw[n * 2 + 1] = w1;
}

__global__ void zero_counts(int* c) { if (threadIdx.x < NEXP) c[threadIdx.x] = 0; }

// ---------------- combine: h += eo[slot0] + eo[slot1] ----------------
__global__ __launch_bounds__(256) void combine_kernel(float* __restrict__ h,
                                                      const float* __restrict__ eo) {
  int i = blockIdx.x * 256 + threadIdx.x;
  int n = i / DMODEL, d = i - n * DMODEL;
  h[i] += eo[(size_t)(n * 2) * DMODEL + d] + eo[(size_t)(n * 2 + 1) * DMODEL + d];
}

extern "C" void kernel_launch(void* const* d_in, const int* in_sizes, int n_in,
                              void* d_out, int out_size, void* d_ws, size_t ws_size,
                              hipStream_t stream) {
  const int*   x       = (const int*)d_in[0];
  const float* tok_emb = (const float*)d_in[1];
  const float* pos_emb = (const float*)d_in[2];
  const float* ln1_g   = (const float*)d_in[3];
  const float* ln1_b   = (const float*)d_in[4];
  const float* qkv_w   = (const float*)d_in[5];
  const float* qkv_b   = (const float*)d_in[6];
  const float* proj_w  = (const float*)d_in[7];
  const float* proj_b  = (const float*)d_in[8];
  const float* ln2_g   = (const float*)d_in[9];
  const float* ln2_b   = (const float*)d_in[10];
  const float* gate_w  = (const float*)d_in[11];
  const float* gate_b  = (const float*)d_in[12];
  const float* w1      = (const float*)d_in[13];
  const float* b1      = (const float*)d_in[14];
  const float* w2      = (const float*)d_in[15];
  const float* b2      = (const float*)d_in[16];
  const float* lnf_g   = (const float*)d_in[17];
  const float* lnf_b   = (const float*)d_in[18];
  float* out = (float*)d_out;

  const size_t ND = (size_t)NTOK * DMODEL;            // 3,145,728 floats
  float* h    = (float*)d_ws;
  float* xln  = h + ND;
  float* R    = xln + ND;                              // qkv (3*ND) / H1 (2N*DHID)
  float* R2   = R + (size_t)2 * NTOK * DHID;           // attn_out (ND) / eo (2N*D)
  float* tokw = R2 + (size_t)2 * NTOK * DMODEL;
  int* counts  = (int*)(tokw + 2 * NTOK);
  int* entries = counts + NEXP;

  float* qkvbuf   = R;
  float* H1       = R;
  float* attn_out = R2;
  float* eo       = R2;

  dim3 blk(256);
  embed_kernel<<<ND / 256, blk, 0, stream>>>(x, tok_emb, pos_emb, h);
  for (int l = 0; l < NLAYER; l++) {
    ln_kernel<<<NTOK, blk, 0, stream>>>(h, ln1_g + l * DMODEL, ln1_b + l * DMODEL, xln);
    gemm_std<false, false><<<dim3(36, 64), blk, 0, stream>>>(
        xln, qkv_w + (size_t)l * DMODEL * 3 * DMODEL, qkv_b + l * 3 * DMODEL,
        qkvbuf, NTOK, 3 * DMODEL, DMODEL);
    fattn_kernel<<<dim3(SEQ / 64, NHEAD, 4), blk, 0, stream>>>(qkvbuf, attn_out);
    gemm_std<false, true><<<dim3(12, 64), blk, 0, stream>>>(
        attn_out, proj_w + (size_t)l * DMODEL * DMODEL, proj_b + l * DMODEL,
        h, NTOK, DMODEL, DMODEL);
    ln_kernel<<<NTOK, blk, 0, stream>>>(h, ln2_g + l * DMODEL, ln2_b + l * DMODEL, xln);
    zero_counts<<<1, 64, 0, stream>>>(counts);
    gate_kernel<<<NTOK / 256, blk, 0, stream>>>(
        xln, gate_w + (size_t)l * DMODEL * NEXP, gate_b + l * NEXP, counts, entries, tokw);
    gemm_moe<true, false><<<dim3(DHID / 64, 64, NEXP), blk, 0, stream>>>(
        xln, w1 + (size_t)l * NEXP * DMODEL * DHID, b1 + (size_t)l * NEXP * DHID,
        H1, entries, counts, tokw, DHID, DMODEL);
    gemm_moe<false, true><<<dim3(DMODEL / 64, 64, NEXP), blk, 0, stream>>>(
        H1, w2 + (size_t)l * NEXP * DHID * DMODEL, b2 + (size_t)l * NEXP * DMODEL,
        eo, entries, counts, tokw, DMODEL, DHID);
    combine_kernel<<<ND / 256, blk, 0, stream>>>(h, eo);
  }
  ln_kernel<<<NTOK, blk, 0, stream>>>(h, lnf_g, lnf_b, xln);
  gemm_std<true, false><<<dim3(VOCAB / 64, 64), blk, 0, stream>>>(
      xln, tok_emb, nullptr, out, NTOK, VOCAB, DMODEL);
}